// Round 6
// baseline (141.235 us; speedup 1.0000x reference)
//
#include <hip/hip_runtime.h>
#include <hip/hip_bf16.h>

#define SIZE 4096
#define BM 256
#define BK 64
#define NT (SIZE / BK)     // 64 K-tiles
#define NBG (SIZE / BM)    // 16x16 grid of 256^2 tiles

typedef __bf16 bf16x8 __attribute__((ext_vector_type(8)));
typedef __bf16 bf16x4 __attribute__((ext_vector_type(4)));
typedef float f32x4 __attribute__((ext_vector_type(4)));
typedef float f32x16 __attribute__((ext_vector_type(16)));

// ---------------------------------------------------------------------------
// async global->LDS, 16B/lane: LDS dest = wave-uniform base + lane*16 (HW).
// ---------------------------------------------------------------------------
__device__ __forceinline__ void gload_lds16(const void* gsrc, void* ldst) {
  __builtin_amdgcn_global_load_lds(
      (const __attribute__((address_space(1))) unsigned int*)gsrc,
      (__attribute__((address_space(3))) unsigned int*)ldst, 16, 0, 0);
}

// ---------------------------------------------------------------------------
// Kernel 1: build L (bf16). One 256-thread block per row. 4 cols/thread
// (1024-col chunks): 4 iterations, 8 barriers total. fp32 throughout
// (matches reference underflow).
// ---------------------------------------------------------------------------
__global__ __launch_bounds__(256) void build_L(const float* __restrict__ p,
                                               __bf16* __restrict__ Lb) {
  const int row = blockIdx.x;
  const int tid = threadIdx.x;
  const int lane = tid & 63;
  const int wid = tid >> 6;
  const long base = (long)row * (row - 1) / 2;

  __shared__ float wtot[4];
  float carry = 1.0f;

  for (int j0 = 0; j0 < SIZE; j0 += 1024) {
    const int jb = j0 + tid * 4;
    if (j0 > row) {  // block-uniform: whole chunk past the diagonal
      bf16x4 z = {(__bf16)0.0f, (__bf16)0.0f, (__bf16)0.0f, (__bf16)0.0f};
      *(bf16x4*)&Lb[(size_t)row * SIZE + jb] = z;
      continue;
    }
    float t[4], v[4];
#pragma unroll
    for (int e = 0; e < 4; ++e) {
      const int j = jb + e;
      if (j < row) {
        const float th = tanhf(p[base + j]);
        t[e] = th;
        v[e] = 1.0f - th * th;
      } else {
        t[e] = (j == row) ? 1.0f : 0.0f;  // diag z=1, upper 0
        v[e] = 1.0f;
      }
    }
    const float vt = v[0] * v[1] * v[2] * v[3];
    float incl = vt;
#pragma unroll
    for (int off = 1; off < 64; off <<= 1) {
      float o = __shfl_up(incl, off, 64);
      if (lane >= off) incl *= o;
    }
    if (lane == 63) wtot[wid] = incl;
    __syncthreads();
    float pre = carry;
    for (int w = 0; w < wid; ++w) pre *= wtot[w];
    float excl = __shfl_up(incl, 1, 64);
    if (lane == 0) excl = 1.0f;
    float s = pre * excl;  // exclusive prefix up to jb
    bf16x4 out;
#pragma unroll
    for (int e = 0; e < 4; ++e) {
      out[e] = (__bf16)(t[e] * sqrtf(s));
      s *= v[e];
    }
    *(bf16x4*)&Lb[(size_t)row * SIZE + jb] = out;
    const float tot = wtot[0] * wtot[1] * wtot[2] * wtot[3];
    __syncthreads();
    carry *= tot;
  }
}

// ---------------------------------------------------------------------------
// Kernel 2: C = L*L^T, 256x256 tile, BK=64, 8 waves (2Mx4N), 4-phase/K-tile
// (m201 skeleton, verified R4/R5). Changes vs R5:
//  - mfma_f32_32x32x16_bf16 (half the MFMA instrs, -17% MFMA floor).
//    Frag: row/col = lane&31, 8 contiguous k at (lane>>5)*8. C/D per m74/m101.
//  - rolling per-stream stage pointers (static phase->stream map, no per-phase
//    address decode). Streams: 0=A-kh0, 1=B-kh0, 2=A-kh1, 3=B-kh1.
// T2 chunk-XOR swizzle kept: slot = (row*4 + chunk^((row>>1)&3))&7 -> exactly
// 8 lanes/slot per b128 read (wave64 floor, 0 conflicts).
// ---------------------------------------------------------------------------
__global__ __launch_bounds__(512, 1) void syrk8(const __bf16* __restrict__ Lb,
                                                float* __restrict__ C) {
  // [buf][ab][kh][row][k] : 2*2*2*256*32*2B = 128 KiB
  __shared__ __bf16 lds[2][2][2][256][32];

  // XCD-chunk swizzle (bijective: 256 % 8 == 0)
  const int bid0 = blockIdx.x;
  const int bid = (bid0 & 7) * 32 + (bid0 >> 3);
  const int bi = bid >> 4, bj = bid & 15;

  const int tid = threadIdx.x;
  const int lane = tid & 63;
  const int wid = tid >> 6;  // 0..7
  const int wm = wid >> 2;   // 0..1 : rows wm*128..+127
  const int wn = wid & 3;    // 0..3 : cols wn*64..+63
  const int r32 = lane & 31;
  const int khi = lane >> 5;  // k-group (8 contiguous bf16)
  // swizzled 16B-chunk offsets for the two 16-k steps within a 32-k half
  const int swz = (r32 >> 1) & 3;
  const int ck0 = ((0 + khi) ^ swz) * 8;  // ks=0: chunk 0|1
  const int ck1 = ((2 + khi) ^ swz) * 8;  // ks=1: chunk 2|3

  const size_t rowA0 = (size_t)bi * 256;
  const size_t rowB0 = (size_t)bj * 256;

  // staging: wave stages 16 rows (64B each) per issue, 2 issues per half-tile
  const int srow = wid * 32 + (lane >> 2);
  const int schunk = (lane & 3) ^ ((lane >> 3) & 3);  // inverse-swz source

  // rolling per-stream global pointers (advance += BK per staged tile)
  const __bf16* g0 = Lb + (rowA0 + srow) * SIZE + schunk * 8;        // A kh0
  const __bf16* g1 = Lb + (rowB0 + srow) * SIZE + schunk * 8;        // B kh0
  const __bf16* g2 = Lb + (rowA0 + srow) * SIZE + 32 + schunk * 8;   // A kh1
  const __bf16* g3 = Lb + (rowB0 + srow) * SIZE + 32 + schunk * 8;   // B kh1

  auto stg = [&](const __bf16*& gp, int ab, int kh, int dstbuf) {
    __bf16* base = &lds[dstbuf][ab][kh][0][0];
#pragma unroll
    for (int q = 0; q < 2; ++q)
      gload_lds16(gp + (size_t)q * 16 * SIZE, base + (wid * 32 + q * 16) * 32);
    gp += BK;
  };

  f32x16 acc[4][2] = {};

  // prologue: tile0 (4 halves, buf0) + tile1's first 3 halves (buf1)
  stg(g0, 0, 0, 0); stg(g1, 1, 0, 0); stg(g2, 0, 1, 0); stg(g3, 1, 1, 0);
  stg(g0, 0, 0, 1); stg(g1, 1, 0, 1); stg(g2, 0, 1, 1);
  asm volatile("s_waitcnt vmcnt(6)" ::: "memory");  // tile0 landed
  __builtin_amdgcn_s_barrier();

  for (int t = 0; t < NT; ++t) {
    const int buf = t & 1, nbuf = buf ^ 1;
    bf16x8 af[2][2], bf[2][2];  // [block][ks]
#pragma unroll
    for (int i = 0; i < 4; ++i) {  // phase: (kh, mh) = (i>>1, i&1)
      const int kh = i >> 1, mh = i & 1;
      if (mh == 0) {  // B-frags for this kh: live across both m-half phases
#pragma unroll
        for (int nb = 0; nb < 2; ++nb) {
          const __bf16* bp = &lds[buf][1][kh][wn * 64 + nb * 32 + r32][0];
          bf[nb][0] = *(const bf16x8*)(bp + ck0);
          bf[nb][1] = *(const bf16x8*)(bp + ck1);
        }
      }
#pragma unroll
      for (int mb = 0; mb < 2; ++mb) {
        const __bf16* ap =
            &lds[buf][0][kh][wm * 128 + (mh * 2 + mb) * 32 + r32][0];
        af[mb][0] = *(const bf16x8*)(ap + ck0);
        af[mb][1] = *(const bf16x8*)(ap + ck1);
      }

      // stage (static phase->stream map): i=0 -> tile t+1 s3; i>=1 -> t+2
      if (i == 0)      { if (t < NT - 1) stg(g3, 1, 1, nbuf); }
      else if (i == 1) { if (t < NT - 2) stg(g0, 0, 0, buf); }
      else if (i == 2) { if (t < NT - 2) stg(g1, 1, 0, buf); }
      else             { if (t < NT - 2) stg(g2, 0, 1, buf); }

      if (i == 3) {  // once per K-tile: gate next tile's data
        if (t == NT - 2)
          asm volatile("s_waitcnt vmcnt(0)" ::: "memory");
        else if (t < NT - 2)
          asm volatile("s_waitcnt vmcnt(6)" ::: "memory");
      }
      __builtin_amdgcn_s_barrier();
      asm volatile("s_waitcnt lgkmcnt(0)" ::: "memory");
      __builtin_amdgcn_sched_barrier(0);
      __builtin_amdgcn_s_setprio(1);
#pragma unroll
      for (int mb = 0; mb < 2; ++mb)
#pragma unroll
        for (int nb = 0; nb < 2; ++nb)
#pragma unroll
          for (int ks = 0; ks < 2; ++ks)
            acc[mh * 2 + mb][nb] = __builtin_amdgcn_mfma_f32_32x32x16_bf16(
                af[mb][ks], bf[nb][ks], acc[mh * 2 + mb][nb], 0, 0, 0);
      __builtin_amdgcn_s_setprio(0);
      __builtin_amdgcn_s_barrier();
    }
  }

  // C/D layout (m74/m101): col = lane&31, row = (j&3) + 8*(j>>2) + 4*(lane>>5)
  float* Cp = C + (rowA0 + wm * 128) * (size_t)SIZE + rowB0 + wn * 64;
#pragma unroll
  for (int mb = 0; mb < 4; ++mb)
#pragma unroll
    for (int nb = 0; nb < 2; ++nb)
#pragma unroll
      for (int j = 0; j < 16; ++j)
        Cp[(size_t)(mb * 32 + (j & 3) + 8 * (j >> 2) + 4 * khi) * SIZE +
           nb * 32 + r32] = acc[mb][nb][j];
}

// ---------------------------------------------------------------------------
extern "C" void kernel_launch(void* const* d_in, const int* in_sizes, int n_in,
                              void* d_out, int out_size, void* d_ws, size_t ws_size,
                              hipStream_t stream) {
  const float* p = (const float*)d_in[0];
  float* C = (float*)d_out;
  __bf16* Lb = (__bf16*)d_ws;  // 32 MB scratch

  build_L<<<SIZE, 256, 0, stream>>>(p, Lb);
  syrk8<<<NBG * NBG, 512, 0, stream>>>(Lb, C);
}

// Round 7
// 134.130 us; speedup vs baseline: 1.0530x; 1.0530x over previous
//
#include <hip/hip_runtime.h>
#include <hip/hip_bf16.h>

#define SIZE 4096
#define BM 256
#define BK 64
#define NT (SIZE / BK)     // 64 K-tiles
#define NBG (SIZE / BM)    // 16x16 grid of 256^2 tiles

typedef __bf16 bf16x8 __attribute__((ext_vector_type(8)));
typedef __bf16 bf16x4 __attribute__((ext_vector_type(4)));
typedef float f32x4 __attribute__((ext_vector_type(4)));
typedef float f32x16 __attribute__((ext_vector_type(16)));

// ---------------------------------------------------------------------------
// async global->LDS, 16B/lane: LDS dest = wave-uniform base + lane*16 (HW).
// ---------------------------------------------------------------------------
__device__ __forceinline__ void gload_lds16(const void* gsrc, void* ldst) {
  __builtin_amdgcn_global_load_lds(
      (const __attribute__((address_space(1))) unsigned int*)gsrc,
      (__attribute__((address_space(3))) unsigned int*)ldst, 16, 0, 0);
}

// ---------------------------------------------------------------------------
// Kernel 1: build L (bf16). One 256-thread block per row. 4 cols/thread
// (1024-col chunks). fp32 throughout (matches reference underflow).
// ---------------------------------------------------------------------------
__global__ __launch_bounds__(256) void build_L(const float* __restrict__ p,
                                               __bf16* __restrict__ Lb) {
  const int row = blockIdx.x;
  const int tid = threadIdx.x;
  const int lane = tid & 63;
  const int wid = tid >> 6;
  const long base = (long)row * (row - 1) / 2;

  __shared__ float wtot[4];
  float carry = 1.0f;

  for (int j0 = 0; j0 < SIZE; j0 += 1024) {
    const int jb = j0 + tid * 4;
    if (j0 > row) {  // block-uniform: whole chunk past the diagonal
      bf16x4 z = {(__bf16)0.0f, (__bf16)0.0f, (__bf16)0.0f, (__bf16)0.0f};
      *(bf16x4*)&Lb[(size_t)row * SIZE + jb] = z;
      continue;
    }
    float t[4], v[4];
#pragma unroll
    for (int e = 0; e < 4; ++e) {
      const int j = jb + e;
      if (j < row) {
        const float th = tanhf(p[base + j]);
        t[e] = th;
        v[e] = 1.0f - th * th;
      } else {
        t[e] = (j == row) ? 1.0f : 0.0f;  // diag z=1, upper 0
        v[e] = 1.0f;
      }
    }
    const float vt = v[0] * v[1] * v[2] * v[3];
    float incl = vt;
#pragma unroll
    for (int off = 1; off < 64; off <<= 1) {
      float o = __shfl_up(incl, off, 64);
      if (lane >= off) incl *= o;
    }
    if (lane == 63) wtot[wid] = incl;
    __syncthreads();
    float pre = carry;
    for (int w = 0; w < wid; ++w) pre *= wtot[w];
    float excl = __shfl_up(incl, 1, 64);
    if (lane == 0) excl = 1.0f;
    float s = pre * excl;  // exclusive prefix up to jb
    bf16x4 out;
#pragma unroll
    for (int e = 0; e < 4; ++e) {
      out[e] = (__bf16)(t[e] * sqrtf(s));
      s *= v[e];
    }
    *(bf16x4*)&Lb[(size_t)row * SIZE + jb] = out;
    const float tot = wtot[0] * wtot[1] * wtot[2] * wtot[3];
    __syncthreads();
    carry *= tot;
  }
}

// ---------------------------------------------------------------------------
// Kernel 2: C = L*L^T, 256x256 tile, BK=64, 8 waves (2Mx4N), 4-phase/K-tile
// (m201 skeleton, verified R4/R5/R6). 32x32x16 MFMA + rolling stage pointers
// (R6). Swizzle FIX vs R6: storage XOR f(row) = ((row>>1)&3) ^ ((row>>4)&1).
// The extra row-bit-4 term makes the read-slot function period-16 within each
// 32-lane half (R6's lane>>5 selector left it period-8 -> half-wave aliasing,
// 1.26e7 conflicts). Store side: staged row has (row>>4)&1 == q, so the
// global-source chunk gains ^q — two precomputed lane constants.
// ---------------------------------------------------------------------------
__global__ __launch_bounds__(512, 1) void syrk8(const __bf16* __restrict__ Lb,
                                                float* __restrict__ C) {
  // [buf][ab][kh][row][k] : 2*2*2*256*32*2B = 128 KiB
  __shared__ __bf16 lds[2][2][2][256][32];

  // XCD-chunk swizzle (bijective: 256 % 8 == 0)
  const int bid0 = blockIdx.x;
  const int bid = (bid0 & 7) * 32 + (bid0 >> 3);
  const int bi = bid >> 4, bj = bid & 15;

  const int tid = threadIdx.x;
  const int lane = tid & 63;
  const int wid = tid >> 6;  // 0..7
  const int wm = wid >> 2;   // 0..1 : rows wm*128..+127
  const int wn = wid & 3;    // 0..3 : cols wn*64..+63
  const int r32 = lane & 31;
  const int khi = lane >> 5;  // k-group (8 contiguous bf16)
  // read-side swizzle: f = ((row>>1)&3) ^ ((row>>4)&1); row = 32*m + r32
  const int swzf = ((r32 >> 1) & 3) ^ ((lane >> 4) & 1);
  const int ck0 = ((0 | khi) ^ swzf) * 8;  // logical chunk khi   (ks=0)
  const int ck1 = ((2 | khi) ^ swzf) * 8;  // logical chunk 2+khi (ks=1)

  const size_t rowA0 = (size_t)bi * 256;
  const size_t rowB0 = (size_t)bj * 256;

  // staging: wave stages 16 rows (64B) per issue, 2 issues per half-tile.
  // lane writes store-chunk (lane&3) of row wid*32 + q*16 + (lane>>2);
  // logical chunk there = (lane&3) ^ ((lane>>3)&3) ^ q.
  const int srow = wid * 32 + (lane >> 2);
  const int sch = (lane & 3) ^ ((lane >> 3) & 3);
  const int soff0 = sch * 8;        // q=0 element offset within row
  const int soff1 = (sch ^ 1) * 8;  // q=1

  // rolling per-stream global pointers (advance += BK per staged tile)
  const __bf16* g0 = Lb + (rowA0 + srow) * SIZE;       // A kh0
  const __bf16* g1 = Lb + (rowB0 + srow) * SIZE;       // B kh0
  const __bf16* g2 = Lb + (rowA0 + srow) * SIZE + 32;  // A kh1
  const __bf16* g3 = Lb + (rowB0 + srow) * SIZE + 32;  // B kh1

  auto stg = [&](const __bf16*& gp, int ab, int kh, int dstbuf) {
    __bf16* base = &lds[dstbuf][ab][kh][0][0];
    gload_lds16(gp + soff0, base + (wid * 32) * 32);
    gload_lds16(gp + (size_t)16 * SIZE + soff1, base + (wid * 32 + 16) * 32);
    gp += BK;
  };

  f32x16 acc[4][2] = {};

  // prologue: tile0 (4 halves, buf0) + tile1's first 3 halves (buf1)
  stg(g0, 0, 0, 0); stg(g1, 1, 0, 0); stg(g2, 0, 1, 0); stg(g3, 1, 1, 0);
  stg(g0, 0, 0, 1); stg(g1, 1, 0, 1); stg(g2, 0, 1, 1);
  asm volatile("s_waitcnt vmcnt(6)" ::: "memory");  // tile0 landed
  __builtin_amdgcn_s_barrier();

  for (int t = 0; t < NT; ++t) {
    const int buf = t & 1, nbuf = buf ^ 1;
    bf16x8 af[2][2], bf[2][2];  // [block][ks]
#pragma unroll
    for (int i = 0; i < 4; ++i) {  // phase: (kh, mh) = (i>>1, i&1)
      const int kh = i >> 1, mh = i & 1;
      if (mh == 0) {  // B-frags for this kh: live across both m-half phases
#pragma unroll
        for (int nb = 0; nb < 2; ++nb) {
          const __bf16* bp = &lds[buf][1][kh][wn * 64 + nb * 32 + r32][0];
          bf[nb][0] = *(const bf16x8*)(bp + ck0);
          bf[nb][1] = *(const bf16x8*)(bp + ck1);
        }
      }
#pragma unroll
      for (int mb = 0; mb < 2; ++mb) {
        const __bf16* ap =
            &lds[buf][0][kh][wm * 128 + (mh * 2 + mb) * 32 + r32][0];
        af[mb][0] = *(const bf16x8*)(ap + ck0);
        af[mb][1] = *(const bf16x8*)(ap + ck1);
      }

      // stage (static phase->stream map): i=0 -> tile t+1 s3; i>=1 -> t+2
      if (i == 0)      { if (t < NT - 1) stg(g3, 1, 1, nbuf); }
      else if (i == 1) { if (t < NT - 2) stg(g0, 0, 0, buf); }
      else if (i == 2) { if (t < NT - 2) stg(g1, 1, 0, buf); }
      else             { if (t < NT - 2) stg(g2, 0, 1, buf); }

      if (i == 3) {  // once per K-tile: gate next tile's data
        if (t == NT - 2)
          asm volatile("s_waitcnt vmcnt(0)" ::: "memory");
        else if (t < NT - 2)
          asm volatile("s_waitcnt vmcnt(6)" ::: "memory");
      }
      __builtin_amdgcn_s_barrier();
      asm volatile("s_waitcnt lgkmcnt(0)" ::: "memory");
      __builtin_amdgcn_sched_barrier(0);
      __builtin_amdgcn_s_setprio(1);
#pragma unroll
      for (int mb = 0; mb < 2; ++mb)
#pragma unroll
        for (int nb = 0; nb < 2; ++nb)
#pragma unroll
          for (int ks = 0; ks < 2; ++ks)
            acc[mh * 2 + mb][nb] = __builtin_amdgcn_mfma_f32_32x32x16_bf16(
                af[mb][ks], bf[nb][ks], acc[mh * 2 + mb][nb], 0, 0, 0);
      __builtin_amdgcn_s_setprio(0);
      __builtin_amdgcn_s_barrier();
    }
  }

  // C/D layout (m74/m101): col = lane&31, row = (j&3) + 8*(j>>2) + 4*(lane>>5)
  float* Cp = C + (rowA0 + wm * 128) * (size_t)SIZE + rowB0 + wn * 64;
#pragma unroll
  for (int mb = 0; mb < 4; ++mb)
#pragma unroll
    for (int nb = 0; nb < 2; ++nb)
#pragma unroll
      for (int j = 0; j < 16; ++j)
        Cp[(size_t)(mb * 32 + (j & 3) + 8 * (j >> 2) + 4 * khi) * SIZE +
           nb * 32 + r32] = acc[mb][nb][j];
}

// ---------------------------------------------------------------------------
extern "C" void kernel_launch(void* const* d_in, const int* in_sizes, int n_in,
                              void* d_out, int out_size, void* d_ws, size_t ws_size,
                              hipStream_t stream) {
  const float* p = (const float*)d_in[0];
  float* C = (float*)d_out;
  __bf16* Lb = (__bf16*)d_ws;  // 32 MB scratch

  build_L<<<SIZE, 256, 0, stream>>>(p, Lb);
  syrk8<<<NBG * NBG, 512, 0, stream>>>(Lb, C);
}